// Round 1
// 352.558 us; speedup vs baseline: 1.2488x; 1.2488x over previous
//
#include <hip/hip_runtime.h>
#include <hip/hip_bf16.h>
#include <stdint.h>

#define BATCH   2048
#define NIN     2048
#define NGATES  8192
#define NCOL    16384   // NGATES*2

typedef short s16x8 __attribute__((ext_vector_type(8)));   // 8 bf16 (4 VGPRs)
typedef float f32x4 __attribute__((ext_vector_type(4)));

__device__ __forceinline__ void gload_lds16(const void* g, void* l) {
  __builtin_amdgcn_global_load_lds(
      (const __attribute__((address_space(1))) void*)g,
      (__attribute__((address_space(3))) void*)l,
      16, 0, 0);
}

__device__ __forceinline__ unsigned short f2bf(float f) {
  __hip_bfloat16 h = __float2bfloat16(f);
  return __builtin_bit_cast(unsigned short, h);
}
__device__ __forceinline__ float bf2f(unsigned int u) {
  return __bfloat162float(__builtin_bit_cast(__hip_bfloat16,
                                             (unsigned short)(u & 0xffff)));
}

// ---------------------------------------------------------------------------
// Kernel 1: per-gate bilinear coefficients from softmax(w[:,g]).
// out = P0 + P1*A + P2*B + P3*A*B  (all 16 gates are bilinear in A,B)
// ---------------------------------------------------------------------------
__global__ __launch_bounds__(256) void gate_coeff_k(const float* __restrict__ w,
                                                    float4* __restrict__ coeff) {
  const int g = blockIdx.x * 256 + threadIdx.x;
  float e[16];
  float s = 0.f;
#pragma unroll
  for (int k = 0; k < 16; ++k) { e[k] = __expf(w[k * NGATES + g]); s += e[k]; }
  const float inv = 1.0f / s;
#pragma unroll
  for (int k = 0; k < 16; ++k) e[k] *= inv;
  const float P0 = e[8] + e[9] + e[10] + e[11] + e[12] + e[13] + e[14] + e[15];
  const float P1 = e[2] + e[3] + e[6] + e[7] - e[8] - e[9] - e[12] - e[13];
  const float P2 = e[4] + e[5] + e[6] + e[7] - e[8] - e[9] - e[10] - e[11];
  const float P3 = e[1] - e[2] - e[4] - 2.f * e[6] - e[7] + e[8] + 2.f * e[9]
                 + e[11] + e[13] - e[14];
  coeff[g] = make_float4(P0, P1, P2, P3);
}

// ---------------------------------------------------------------------------
// Kernel 2: x (fp32) -> bf16, row-major [B][K]
// ---------------------------------------------------------------------------
__global__ __launch_bounds__(256) void cvt_x_k(const float4* __restrict__ x,
                                               ushort4* __restrict__ xb) {
  const int i = blockIdx.x * 256 + threadIdx.x;
  float4 v = x[i];
  ushort4 h;
  h.x = f2bf(v.x); h.y = f2bf(v.y); h.z = f2bf(v.z); h.w = f2bf(v.w);
  xb[i] = h;
}

// ---------------------------------------------------------------------------
// Kernel 3: e = exp(c) bf16, transposed to bT[n][k]. Barrier-free register
// transpose; per-column partial sums of the bf16-rounded values.
// Grid: (NCOL/64, 4 row-quarters of 512).
// ---------------------------------------------------------------------------
__global__ __launch_bounds__(256) void softmax_t_k(const float* __restrict__ c,
                                                   unsigned short* __restrict__ bT,
                                                   float* __restrict__ psums) {
  __shared__ float red[16][68];
  const int t = threadIdx.x;
  const int ng = (t & 15) * 4;   // 4 consecutive cols
  const int kg = t >> 4;         // 0..15: 8-row chunk
  const int n0 = blockIdx.x * 64;
  const int q  = blockIdx.y;
  const float* cb = c + (size_t)n0 + ng;
  float s0 = 0.f, s1 = 0.f, s2 = 0.f, s3 = 0.f;

  float4 v[8], nv[8];
  {
    const int r0 = q * 512 + kg * 8;
#pragma unroll
    for (int d = 0; d < 8; ++d)
      v[d] = *(const float4*)&cb[(size_t)(r0 + d) * NCOL];
  }
  for (int it = 0; it < 4; ++it) {
    if (it < 3) {
      const int r1 = q * 512 + (it + 1) * 128 + kg * 8;
#pragma unroll
      for (int d = 0; d < 8; ++d)
        nv[d] = *(const float4*)&cb[(size_t)(r1 + d) * NCOL];
    }
    unsigned int u[4][4];   // [col][k-pair]
#pragma unroll
    for (int d2 = 0; d2 < 4; ++d2) {
      float4 e0 = v[2 * d2], e1 = v[2 * d2 + 1];
      unsigned int a0 = f2bf(__expf(e0.x)), b0 = f2bf(__expf(e1.x));
      unsigned int a1 = f2bf(__expf(e0.y)), b1 = f2bf(__expf(e1.y));
      unsigned int a2 = f2bf(__expf(e0.z)), b2 = f2bf(__expf(e1.z));
      unsigned int a3 = f2bf(__expf(e0.w)), b3 = f2bf(__expf(e1.w));
      s0 += bf2f(a0) + bf2f(b0);
      s1 += bf2f(a1) + bf2f(b1);
      s2 += bf2f(a2) + bf2f(b2);
      s3 += bf2f(a3) + bf2f(b3);
      u[0][d2] = a0 | (b0 << 16);
      u[1][d2] = a1 | (b1 << 16);
      u[2][d2] = a2 | (b2 << 16);
      u[3][d2] = a3 | (b3 << 16);
    }
    const int i0 = q * 512 + it * 128 + kg * 8;
#pragma unroll
    for (int j = 0; j < 4; ++j) {
      uint4 pk = make_uint4(u[j][0], u[j][1], u[j][2], u[j][3]);
      *(uint4*)&bT[(size_t)(n0 + ng + j) * NIN + i0] = pk;
    }
    if (it < 3) {
#pragma unroll
      for (int d = 0; d < 8; ++d) v[d] = nv[d];
    }
  }
  red[kg][ng + 0] = s0;
  red[kg][ng + 1] = s1;
  red[kg][ng + 2] = s2;
  red[kg][ng + 3] = s3;
  __syncthreads();
  if (t < 64) {
    float tot = 0.f;
#pragma unroll
    for (int k2 = 0; k2 < 16; ++k2) tot += red[k2][t];
    psums[(size_t)q * NCOL + n0 + t] = tot;
  }
}

// ---------------------------------------------------------------------------
// Kernel 4: fold row-quarter partials -> invsum[n] = 1/sum
// ---------------------------------------------------------------------------
__global__ __launch_bounds__(256) void inv_k(const float* __restrict__ psums,
                                             float* __restrict__ invs) {
  const int n = blockIdx.x * 256 + threadIdx.x;
  invs[n] = 1.0f / (psums[n] + psums[NCOL + n] + psums[2 * NCOL + n] +
                    psums[3 * NCOL + n]);
}

// ---------------------------------------------------------------------------
// Kernel 5: 256x256-tile 8-phase bf16 MFMA GEMM (guide §5 template, m201).
//   BM=BN=256, BK=64, 8 waves (2M x 4N), per-wave 128x64 output, 128KiB LDS
//   (2 K-tile double buffer), 16 MFMA per barrier-pair phase, ONE counted
//   s_waitcnt vmcnt(6) per K-tile (3 stage-units stay in flight), setprio(1)
//   around MFMA clusters, XOR swizzle slot^=(row&7) on 128B LDS rows.
//
// Problem twist: B rows are permuted AT STAGE TIME (per-lane global source
// addresses; LDS dest stays linear per global_load_lds rules) so a wave's
// 64 n-cols = [A-col of 32 gates | B-col of same 32 gates]:
//   B1 unit: lds row lr <- bT row 2*(g0+lr)   (even cols, "A" values)
//   B2 unit: lds row lr <- bT row 2*(g0+lr)+1 (odd  cols, "B" values)
// => acc[i][j] (j=0,1) and acc[i][j+2] hold the (A,B) pair of gate
//    g0+wn*32+j*16+fr in the SAME lane/reg: epilogue is shuffle-free, all
//    64 lanes active, direct coalesced dword stores.
//
// Stage-unit schedule (unit staged for tile t+2 one barrier AFTER its last
// LDS read by tile t): ph0: A2(t+1) [other buf], ph1: A1(t+2),
// ph2: B1(t+2), ph3: B2(t+2) [current buf, slots already dead].
// Invariant: at iteration t start, all of tile t is resident (vmcnt(6) at
// end of t-1 ph3 drains through A2(t)'s loads).
// ---------------------------------------------------------------------------
#define MFMA_B16(a, b, c) __builtin_amdgcn_mfma_f32_16x16x32_bf16(a, b, c, 0, 0, 0)

__global__ __launch_bounds__(512, 2) void gemm_gate_k(
    const unsigned short* __restrict__ xb,   // [2048][2048] bf16
    const unsigned short* __restrict__ bT,   // [16384][2048] bf16
    const float* __restrict__ invs,          // [16384]
    const float4* __restrict__ coeff,        // [8192]
    float* __restrict__ out) {               // [2048][8192]
  extern __shared__ char smem[];             // 131072 B
  constexpr int NT = 32;                     // K / BK = 2048/64

  const int t  = threadIdx.x;                // 0..511
  const int l  = t & 63;
  const int w  = t >> 6;
  const int wm = w >> 2;                     // 0..1: M half
  const int wn = w & 3;                      // 0..3: N quarter
  const int fr = l & 15;
  const int cq = l >> 4;

  // XCD-bijective swizzle (512 % 8 == 0): 8 consecutive local blocks share
  // one gate-panel (L2 resident), sweep m.
  const int bid = blockIdx.x;
  const int xcd = bid & 7;
  const int loc = bid >> 3;                  // 0..63
  const int m0  = (loc & 7) * 256;
  const int g0  = (xcd * 8 + (loc >> 3)) * 128;

  // ---- stage source offsets (elements), inverse-XOR-swizzled + B-permuted
  uint32_t offA[2][2], offB[2][2];           // [unit][round]
#pragma unroll
  for (int r = 0; r < 2; ++r) {
    const int idx = r * 512 + t;             // 0..1023 -> lds (row, slot)
    const int lr  = idx >> 3;
    const int ch  = (idx & 7) ^ (lr & 7);    // chunk stored at this slot
    const int rA  = (lr & 63) + ((lr >> 6) << 7);       // A1: rows 0-63,128-191
    offA[0][r] = (uint32_t)(m0 + rA) * NIN + ch * 8;
    offA[1][r] = offA[0][r] + (uint32_t)64 * NIN;       // A2: +64
    offB[0][r] = (uint32_t)(2 * (g0 + lr)) * NIN + ch * 8;  // even col
    offB[1][r] = offB[0][r] + NIN;                          // odd col
  }

  auto issueA = [&](int u, int tt) {
    char* d = smem + ((tt & 1) << 16) + (u << 14) + t * 16;
    gload_lds16(xb + offA[u][0] + tt * 64, d);
    gload_lds16(xb + offA[u][1] + tt * 64, d + 8192);
  };
  auto issueB = [&](int u, int tt) {
    char* d = smem + ((tt & 1) << 16) + ((2 + u) << 14) + t * 16;
    gload_lds16(bT + offB[u][0] + tt * 64, d);
    gload_lds16(bT + offB[u][1] + tt * 64, d + 8192);
  };

  // ---- fragment read offsets (row*128, slot = chunk ^ (row&7))
  const int aob = (wm * 64 + fr) * 128;          // + unit*16384 + i*2048
  const int bob = 32768 + (wn * 32 + fr) * 128;  // + unit*16384 + j*2048
  const int sx0 = ((cq)     ^ (fr & 7)) * 16;    // ks=0 slot
  const int sx1 = ((cq + 4) ^ (fr & 7)) * 16;    // ks=1 slot

  f32x4 acc[8][4] = {};
  s16x8 af[8];     // current A half: 4 i x 2 ks
  s16x8 bfr[8];    // [0..3]=B1 (j=0,1 x ks), [4..7]=B2 (j=2,3 x ks)

  // ---- prologue: tile0 full + tile1 {A1,B1,B2}; A2(1) comes at kt=0 ph0
  issueA(0, 0); issueA(1, 0); issueB(0, 0); issueB(1, 0);
  issueA(0, 1); issueB(0, 1); issueB(1, 1);
  asm volatile("s_waitcnt vmcnt(6)" ::: "memory");   // tile0 landed
  asm volatile("s_barrier" ::: "memory");

  for (int kt = 0; kt < NT; ++kt) {
    char* rb = smem + ((kt & 1) << 16);

    // ===== phase 0: (i0-3, j0-1) — read A1 + B1, stage A2(kt+1)
#pragma unroll
    for (int i = 0; i < 4; ++i) {
      af[i * 2 + 0] = *(const s16x8*)(rb + aob + i * 2048 + sx0);
      af[i * 2 + 1] = *(const s16x8*)(rb + aob + i * 2048 + sx1);
    }
#pragma unroll
    for (int j = 0; j < 2; ++j) {
      bfr[j * 2 + 0] = *(const s16x8*)(rb + bob + j * 2048 + sx0);
      bfr[j * 2 + 1] = *(const s16x8*)(rb + bob + j * 2048 + sx1);
    }
    if (kt + 1 < NT) issueA(1, kt + 1);
    asm volatile("s_barrier" ::: "memory");
    asm volatile("s_waitcnt lgkmcnt(0)" ::: "memory");
    __builtin_amdgcn_s_setprio(1);
#pragma unroll
    for (int i = 0; i < 4; ++i)
#pragma unroll
      for (int j = 0; j < 2; ++j) {
        acc[i][j] = MFMA_B16(af[i * 2 + 0], bfr[j * 2 + 0], acc[i][j]);
        acc[i][j] = MFMA_B16(af[i * 2 + 1], bfr[j * 2 + 1], acc[i][j]);
      }
    __builtin_amdgcn_s_setprio(0);
    asm volatile("s_barrier" ::: "memory");

    // ===== phase 1: (i0-3, j2-3) — read B2, stage A1(kt+2)
#pragma unroll
    for (int j = 0; j < 2; ++j) {
      bfr[4 + j * 2 + 0] = *(const s16x8*)(rb + bob + 16384 + j * 2048 + sx0);
      bfr[4 + j * 2 + 1] = *(const s16x8*)(rb + bob + 16384 + j * 2048 + sx1);
    }
    if (kt + 2 < NT) issueA(0, kt + 2);
    asm volatile("s_barrier" ::: "memory");
    asm volatile("s_waitcnt lgkmcnt(0)" ::: "memory");
    __builtin_amdgcn_s_setprio(1);
#pragma unroll
    for (int i = 0; i < 4; ++i)
#pragma unroll
      for (int j = 0; j < 2; ++j) {
        acc[i][2 + j] = MFMA_B16(af[i * 2 + 0], bfr[4 + j * 2 + 0], acc[i][2 + j]);
        acc[i][2 + j] = MFMA_B16(af[i * 2 + 1], bfr[4 + j * 2 + 1], acc[i][2 + j]);
      }
    __builtin_amdgcn_s_setprio(0);
    asm volatile("s_barrier" ::: "memory");

    // ===== phase 2: (i4-7, j2-3) — read A2 into af, stage B1(kt+2)
#pragma unroll
    for (int i = 0; i < 4; ++i) {
      af[i * 2 + 0] = *(const s16x8*)(rb + 16384 + aob + i * 2048 + sx0);
      af[i * 2 + 1] = *(const s16x8*)(rb + 16384 + aob + i * 2048 + sx1);
    }
    if (kt + 2 < NT) issueB(0, kt + 2);
    asm volatile("s_barrier" ::: "memory");
    asm volatile("s_waitcnt lgkmcnt(0)" ::: "memory");
    __builtin_amdgcn_s_setprio(1);
#pragma unroll
    for (int i = 0; i < 4; ++i)
#pragma unroll
      for (int j = 0; j < 2; ++j) {
        acc[4 + i][2 + j] = MFMA_B16(af[i * 2 + 0], bfr[4 + j * 2 + 0], acc[4 + i][2 + j]);
        acc[4 + i][2 + j] = MFMA_B16(af[i * 2 + 1], bfr[4 + j * 2 + 1], acc[4 + i][2 + j]);
      }
    __builtin_amdgcn_s_setprio(0);
    asm volatile("s_barrier" ::: "memory");

    // ===== phase 3: (i4-7, j0-1) — no reads (af=A2, bfr[0..3]=B1 kept),
    //                stage B2(kt+2), counted vmcnt at tile end
    if (kt + 2 < NT) issueB(1, kt + 2);
    asm volatile("s_barrier" ::: "memory");
    asm volatile("s_waitcnt lgkmcnt(0)" ::: "memory");
    __builtin_amdgcn_s_setprio(1);
#pragma unroll
    for (int i = 0; i < 4; ++i)
#pragma unroll
      for (int j = 0; j < 2; ++j) {
        acc[4 + i][j] = MFMA_B16(af[i * 2 + 0], bfr[j * 2 + 0], acc[4 + i][j]);
        acc[4 + i][j] = MFMA_B16(af[i * 2 + 1], bfr[j * 2 + 1], acc[4 + i][j]);
      }
    __builtin_amdgcn_s_setprio(0);
    if (kt < NT - 2) {
      asm volatile("s_waitcnt vmcnt(6)" ::: "memory");  // tile kt+1 resident
    } else {
      asm volatile("s_waitcnt vmcnt(0)" ::: "memory");  // drain tail
    }
    asm volatile("s_barrier" ::: "memory");
  }

  // ---- epilogue: normalize, bilinear gate, direct coalesced stores.
  // acc[i][j]   (j=0,1): A = y[:,2g]  for gate g = g0 + wn*32 + j*16 + fr
  // acc[i][j+2]        : B = y[:,2g+1], same lane/reg — no shuffles.
#pragma unroll
  for (int j = 0; j < 2; ++j) {
    const int gate = g0 + wn * 32 + j * 16 + fr;
    const float2 iv = *(const float2*)&invs[2 * gate];
    const float4 P  = coeff[gate];
#pragma unroll
    for (int i = 0; i < 8; ++i) {
#pragma unroll
      for (int r = 0; r < 4; ++r) {
        const float A = acc[i][j][r]     * iv.x;
        const float B = acc[i][j + 2][r] * iv.y;
        const float res = P.x + P.y * A + P.z * B + P.w * A * B;
        const int m = m0 + wm * 128 + i * 16 + cq * 4 + r;
        out[(size_t)m * NGATES + gate] = res;
      }
    }
  }
}

// ---------------------------------------------------------------------------
extern "C" void kernel_launch(void* const* d_in, const int* in_sizes, int n_in,
                              void* d_out, int out_size, void* d_ws,
                              size_t ws_size, hipStream_t stream) {
  const float* x = (const float*)d_in[0];   // [2048][2048]
  const float* w = (const float*)d_in[1];   // [16][8192]
  const float* c = (const float*)d_in[2];   // [2048][8192][2]
  float* out = (float*)d_out;               // [2048][8192]
  char* ws = (char*)d_ws;

  unsigned short* xb   = (unsigned short*)(ws);               // 8,388,608 B
  unsigned short* bT   = (unsigned short*)(ws + 8388608);     // 67,108,864 B
  float*          invs = (float*)(ws + 75497472);             // 65,536 B
  float4*         cf   = (float4*)(ws + 75563008);            // 131,072 B
  float*          ps   = (float*)(ws + 75694080);             // 262,144 B

  static bool attr_done = false;
  if (!attr_done) {
    (void)hipFuncSetAttribute(reinterpret_cast<const void*>(gemm_gate_k),
                              hipFuncAttributeMaxDynamicSharedMemorySize,
                              131072);
    attr_done = true;
  }

  gate_coeff_k<<<NGATES / 256, 256, 0, stream>>>(w, cf);
  cvt_x_k<<<(BATCH * NIN / 4) / 256, 256, 0, stream>>>((const float4*)x,
                                                       (ushort4*)xb);
  dim3 sg(NCOL / 64, 4);
  softmax_t_k<<<sg, 256, 0, stream>>>(c, bT, ps);
  inv_k<<<NCOL / 256, 256, 0, stream>>>(ps, invs);
  gemm_gate_k<<<512, 512, 131072, stream>>>(xb, bT, invs, cf, out);
}

// Round 2
// 352.443 us; speedup vs baseline: 1.2492x; 1.0003x over previous
//
#include <hip/hip_runtime.h>
#include <hip/hip_bf16.h>
#include <stdint.h>

#define BATCH   2048
#define NIN     2048
#define NGATES  8192
#define NCOL    16384   // NGATES*2

typedef short s16x8 __attribute__((ext_vector_type(8)));   // 8 bf16 (4 VGPRs)
typedef float f32x4 __attribute__((ext_vector_type(4)));

__device__ __forceinline__ void gload_lds16(const void* g, void* l) {
  __builtin_amdgcn_global_load_lds(
      (const __attribute__((address_space(1))) void*)g,
      (__attribute__((address_space(3))) void*)l,
      16, 0, 0);
}

__device__ __forceinline__ unsigned short f2bf(float f) {
  __hip_bfloat16 h = __float2bfloat16(f);
  return __builtin_bit_cast(unsigned short, h);
}
__device__ __forceinline__ float bf2f(unsigned int u) {
  return __bfloat162float(__builtin_bit_cast(__hip_bfloat16,
                                             (unsigned short)(u & 0xffff)));
}

// ---------------------------------------------------------------------------
// Kernel 1: per-gate bilinear coefficients from softmax(w[:,g]).
// out = P0 + P1*A + P2*B + P3*A*B  (all 16 gates are bilinear in A,B)
// ---------------------------------------------------------------------------
__global__ __launch_bounds__(256) void gate_coeff_k(const float* __restrict__ w,
                                                    float4* __restrict__ coeff) {
  const int g = blockIdx.x * 256 + threadIdx.x;
  float e[16];
  float s = 0.f;
#pragma unroll
  for (int k = 0; k < 16; ++k) { e[k] = __expf(w[k * NGATES + g]); s += e[k]; }
  const float inv = 1.0f / s;
#pragma unroll
  for (int k = 0; k < 16; ++k) e[k] *= inv;
  const float P0 = e[8] + e[9] + e[10] + e[11] + e[12] + e[13] + e[14] + e[15];
  const float P1 = e[2] + e[3] + e[6] + e[7] - e[8] - e[9] - e[12] - e[13];
  const float P2 = e[4] + e[5] + e[6] + e[7] - e[8] - e[9] - e[10] - e[11];
  const float P3 = e[1] - e[2] - e[4] - 2.f * e[6] - e[7] + e[8] + 2.f * e[9]
                 + e[11] + e[13] - e[14];
  coeff[g] = make_float4(P0, P1, P2, P3);
}

// ---------------------------------------------------------------------------
// Kernel 2: x (fp32) -> bf16, row-major [B][K]
// ---------------------------------------------------------------------------
__global__ __launch_bounds__(256) void cvt_x_k(const float4* __restrict__ x,
                                               ushort4* __restrict__ xb) {
  const int i = blockIdx.x * 256 + threadIdx.x;
  float4 v = x[i];
  ushort4 h;
  h.x = f2bf(v.x); h.y = f2bf(v.y); h.z = f2bf(v.z); h.w = f2bf(v.w);
  xb[i] = h;
}

// ---------------------------------------------------------------------------
// Kernel 3 (v2): e = exp(c) bf16, transposed to bT[n][k], LDS-staged so the
// global stores are 1KB-contiguous per wave instruction (was: 16 rows x 64B
// scattered at 4KB stride -> DRAM-page-hostile).
//   Phase 1: coalesced c reads (as v1) -> exp -> bf16 -> partial col sums,
//            packed uint4 (8 k) into LDS tile [64 n][512 k] with low-3-bit
//            chunk XOR swizzle (chunk ^ ((row>>2)&7)): write conflicts
//            <=2-way (free), phase-2 reads contiguous.
//   Phase 2: wave w streams rows w*16..w*16+15; lane l writes bytes l*16 of
//            one bT row -> 1KB contiguous per store instruction.
// Grid: (NCOL/64, 4 row-quarters of 512). Dynamic LDS 69888B (2 blocks/CU).
// ---------------------------------------------------------------------------
__global__ __launch_bounds__(256) void softmax_t_k(const float* __restrict__ c,
                                                   unsigned short* __restrict__ bT,
                                                   float* __restrict__ psums) {
  extern __shared__ char sm3[];                 // 65536 tile + 4352 red
  char*  tile = sm3;                            // [64 rows][1024 B]
  float* red  = (float*)(sm3 + 65536);          // [16][68]
  const int t = threadIdx.x;
  const int ng = (t & 15) * 4;   // 4 consecutive cols
  const int kg = t >> 4;         // 0..15: 8-row chunk
  const int n0 = blockIdx.x * 64;
  const int q  = blockIdx.y;
  const float* cb = c + (size_t)n0 + ng;
  float s0 = 0.f, s1 = 0.f, s2 = 0.f, s3 = 0.f;

  float4 v[8], nv[8];
  {
    const int r0 = q * 512 + kg * 8;
#pragma unroll
    for (int d = 0; d < 8; ++d)
      v[d] = *(const float4*)&cb[(size_t)(r0 + d) * NCOL];
  }
  for (int it = 0; it < 4; ++it) {
    if (it < 3) {
      const int r1 = q * 512 + (it + 1) * 128 + kg * 8;
#pragma unroll
      for (int d = 0; d < 8; ++d)
        nv[d] = *(const float4*)&cb[(size_t)(r1 + d) * NCOL];
    }
    unsigned int u[4][4];   // [col][k-pair]
#pragma unroll
    for (int d2 = 0; d2 < 4; ++d2) {
      float4 e0 = v[2 * d2], e1 = v[2 * d2 + 1];
      unsigned int a0 = f2bf(__expf(e0.x)), b0 = f2bf(__expf(e1.x));
      unsigned int a1 = f2bf(__expf(e0.y)), b1 = f2bf(__expf(e1.y));
      unsigned int a2 = f2bf(__expf(e0.z)), b2 = f2bf(__expf(e1.z));
      unsigned int a3 = f2bf(__expf(e0.w)), b3 = f2bf(__expf(e1.w));
      s0 += bf2f(a0) + bf2f(b0);
      s1 += bf2f(a1) + bf2f(b1);
      s2 += bf2f(a2) + bf2f(b2);
      s3 += bf2f(a3) + bf2f(b3);
      u[0][d2] = a0 | (b0 << 16);
      u[1][d2] = a1 | (b1 << 16);
      u[2][d2] = a2 | (b2 << 16);
      u[3][d2] = a3 | (b3 << 16);
    }
    const int chunk = it * 16 + kg;             // 16B chunk index within row
#pragma unroll
    for (int j = 0; j < 4; ++j) {
      const int row = ng + j;
      const int sw  = (chunk & ~7) | ((chunk ^ (row >> 2)) & 7);
      uint4 pk = make_uint4(u[j][0], u[j][1], u[j][2], u[j][3]);
      *(uint4*)&tile[row * 1024 + sw * 16] = pk;
    }
    if (it < 3) {
#pragma unroll
      for (int d = 0; d < 8; ++d) v[d] = nv[d];
    }
  }
  red[kg * 68 + ng + 0] = s0;
  red[kg * 68 + ng + 1] = s1;
  red[kg * 68 + ng + 2] = s2;
  red[kg * 68 + ng + 3] = s3;
  __syncthreads();

  // Phase 2: 1KB-contiguous stores. Wave w -> rows w*16..+15; lane l -> chunk l.
  {
    const int wv = t >> 6;
    const int l  = t & 63;
#pragma unroll
    for (int r16 = 0; r16 < 16; ++r16) {
      const int row = wv * 16 + r16;
      const int sw  = (l & ~7) | ((l ^ (row >> 2)) & 7);
      uint4 vv = *(const uint4*)&tile[row * 1024 + sw * 16];
      *(uint4*)&bT[(size_t)(n0 + row) * NIN + q * 512 + l * 8] = vv;
    }
  }
  if (t < 64) {
    float tot = 0.f;
#pragma unroll
    for (int k2 = 0; k2 < 16; ++k2) tot += red[k2 * 68 + t];
    psums[(size_t)q * NCOL + n0 + t] = tot;
  }
}

// ---------------------------------------------------------------------------
// Kernel 4: fold row-quarter partials -> invsum[n] = 1/sum
// ---------------------------------------------------------------------------
__global__ __launch_bounds__(256) void inv_k(const float* __restrict__ psums,
                                             float* __restrict__ invs) {
  const int n = blockIdx.x * 256 + threadIdx.x;
  invs[n] = 1.0f / (psums[n] + psums[NCOL + n] + psums[2 * NCOL + n] +
                    psums[3 * NCOL + n]);
}

// ---------------------------------------------------------------------------
// Kernel 5: 256x256-tile 8-phase bf16 MFMA GEMM (guide §5 template, m201).
// UNCHANGED from round 1 (131 µs, MfmaUtil 43%, 0 bank conflicts) — kept
// fixed this round to isolate the softmax_t_k rewrite's effect.
// ---------------------------------------------------------------------------
#define MFMA_B16(a, b, c) __builtin_amdgcn_mfma_f32_16x16x32_bf16(a, b, c, 0, 0, 0)

__global__ __launch_bounds__(512, 2) void gemm_gate_k(
    const unsigned short* __restrict__ xb,   // [2048][2048] bf16
    const unsigned short* __restrict__ bT,   // [16384][2048] bf16
    const float* __restrict__ invs,          // [16384]
    const float4* __restrict__ coeff,        // [8192]
    float* __restrict__ out) {               // [2048][8192]
  extern __shared__ char smem[];             // 131072 B
  constexpr int NT = 32;                     // K / BK = 2048/64

  const int t  = threadIdx.x;                // 0..511
  const int l  = t & 63;
  const int w  = t >> 6;
  const int wm = w >> 2;                     // 0..1: M half
  const int wn = w & 3;                      // 0..3: N quarter
  const int fr = l & 15;
  const int cq = l >> 4;

  // XCD-bijective swizzle (512 % 8 == 0): 8 consecutive local blocks share
  // one gate-panel (L2 resident), sweep m.
  const int bid = blockIdx.x;
  const int xcd = bid & 7;
  const int loc = bid >> 3;                  // 0..63
  const int m0  = (loc & 7) * 256;
  const int g0  = (xcd * 8 + (loc >> 3)) * 128;

  // ---- stage source offsets (elements), inverse-XOR-swizzled + B-permuted
  uint32_t offA[2][2], offB[2][2];           // [unit][round]
#pragma unroll
  for (int r = 0; r < 2; ++r) {
    const int idx = r * 512 + t;             // 0..1023 -> lds (row, slot)
    const int lr  = idx >> 3;
    const int ch  = (idx & 7) ^ (lr & 7);    // chunk stored at this slot
    const int rA  = (lr & 63) + ((lr >> 6) << 7);       // A1: rows 0-63,128-191
    offA[0][r] = (uint32_t)(m0 + rA) * NIN + ch * 8;
    offA[1][r] = offA[0][r] + (uint32_t)64 * NIN;       // A2: +64
    offB[0][r] = (uint32_t)(2 * (g0 + lr)) * NIN + ch * 8;  // even col
    offB[1][r] = offB[0][r] + NIN;                          // odd col
  }

  auto issueA = [&](int u, int tt) {
    char* d = smem + ((tt & 1) << 16) + (u << 14) + t * 16;
    gload_lds16(xb + offA[u][0] + tt * 64, d);
    gload_lds16(xb + offA[u][1] + tt * 64, d + 8192);
  };
  auto issueB = [&](int u, int tt) {
    char* d = smem + ((tt & 1) << 16) + ((2 + u) << 14) + t * 16;
    gload_lds16(bT + offB[u][0] + tt * 64, d);
    gload_lds16(bT + offB[u][1] + tt * 64, d + 8192);
  };

  // ---- fragment read offsets (row*128, slot = chunk ^ (row&7))
  const int aob = (wm * 64 + fr) * 128;          // + unit*16384 + i*2048
  const int bob = 32768 + (wn * 32 + fr) * 128;  // + unit*16384 + j*2048
  const int sx0 = ((cq)     ^ (fr & 7)) * 16;    // ks=0 slot
  const int sx1 = ((cq + 4) ^ (fr & 7)) * 16;    // ks=1 slot

  f32x4 acc[8][4] = {};
  s16x8 af[8];     // current A half: 4 i x 2 ks
  s16x8 bfr[8];    // [0..3]=B1 (j=0,1 x ks), [4..7]=B2 (j=2,3 x ks)

  // ---- prologue: tile0 full + tile1 {A1,B1,B2}; A2(1) comes at kt=0 ph0
  issueA(0, 0); issueA(1, 0); issueB(0, 0); issueB(1, 0);
  issueA(0, 1); issueB(0, 1); issueB(1, 1);
  asm volatile("s_waitcnt vmcnt(6)" ::: "memory");   // tile0 landed
  asm volatile("s_barrier" ::: "memory");

  for (int kt = 0; kt < NT; ++kt) {
    char* rb = smem + ((kt & 1) << 16);

    // ===== phase 0: (i0-3, j0-1) — read A1 + B1, stage A2(kt+1)
#pragma unroll
    for (int i = 0; i < 4; ++i) {
      af[i * 2 + 0] = *(const s16x8*)(rb + aob + i * 2048 + sx0);
      af[i * 2 + 1] = *(const s16x8*)(rb + aob + i * 2048 + sx1);
    }
#pragma unroll
    for (int j = 0; j < 2; ++j) {
      bfr[j * 2 + 0] = *(const s16x8*)(rb + bob + j * 2048 + sx0);
      bfr[j * 2 + 1] = *(const s16x8*)(rb + bob + j * 2048 + sx1);
    }
    if (kt + 1 < NT) issueA(1, kt + 1);
    asm volatile("s_barrier" ::: "memory");
    asm volatile("s_waitcnt lgkmcnt(0)" ::: "memory");
    __builtin_amdgcn_s_setprio(1);
#pragma unroll
    for (int i = 0; i < 4; ++i)
#pragma unroll
      for (int j = 0; j < 2; ++j) {
        acc[i][j] = MFMA_B16(af[i * 2 + 0], bfr[j * 2 + 0], acc[i][j]);
        acc[i][j] = MFMA_B16(af[i * 2 + 1], bfr[j * 2 + 1], acc[i][j]);
      }
    __builtin_amdgcn_s_setprio(0);
    asm volatile("s_barrier" ::: "memory");

    // ===== phase 1: (i0-3, j2-3) — read B2, stage A1(kt+2)
#pragma unroll
    for (int j = 0; j < 2; ++j) {
      bfr[4 + j * 2 + 0] = *(const s16x8*)(rb + bob + 16384 + j * 2048 + sx0);
      bfr[4 + j * 2 + 1] = *(const s16x8*)(rb + bob + 16384 + j * 2048 + sx1);
    }
    if (kt + 2 < NT) issueA(0, kt + 2);
    asm volatile("s_barrier" ::: "memory");
    asm volatile("s_waitcnt lgkmcnt(0)" ::: "memory");
    __builtin_amdgcn_s_setprio(1);
#pragma unroll
    for (int i = 0; i < 4; ++i)
#pragma unroll
      for (int j = 0; j < 2; ++j) {
        acc[i][2 + j] = MFMA_B16(af[i * 2 + 0], bfr[4 + j * 2 + 0], acc[i][2 + j]);
        acc[i][2 + j] = MFMA_B16(af[i * 2 + 1], bfr[4 + j * 2 + 1], acc[i][2 + j]);
      }
    __builtin_amdgcn_s_setprio(0);
    asm volatile("s_barrier" ::: "memory");

    // ===== phase 2: (i4-7, j2-3) — read A2 into af, stage B1(kt+2)
#pragma unroll
    for (int i = 0; i < 4; ++i) {
      af[i * 2 + 0] = *(const s16x8*)(rb + 16384 + aob + i * 2048 + sx0);
      af[i * 2 + 1] = *(const s16x8*)(rb + 16384 + aob + i * 2048 + sx1);
    }
    if (kt + 2 < NT) issueB(0, kt + 2);
    asm volatile("s_barrier" ::: "memory");
    asm volatile("s_waitcnt lgkmcnt(0)" ::: "memory");
    __builtin_amdgcn_s_setprio(1);
#pragma unroll
    for (int i = 0; i < 4; ++i)
#pragma unroll
      for (int j = 0; j < 2; ++j) {
        acc[4 + i][2 + j] = MFMA_B16(af[i * 2 + 0], bfr[4 + j * 2 + 0], acc[4 + i][2 + j]);
        acc[4 + i][2 + j] = MFMA_B16(af[i * 2 + 1], bfr[4 + j * 2 + 1], acc[4 + i][2 + j]);
      }
    __builtin_amdgcn_s_setprio(0);
    asm volatile("s_barrier" ::: "memory");

    // ===== phase 3: (i4-7, j0-1) — no reads (af=A2, bfr[0..3]=B1 kept),
    //                stage B2(kt+2), counted vmcnt at tile end
    if (kt + 2 < NT) issueB(1, kt + 2);
    asm volatile("s_barrier" ::: "memory");
    asm volatile("s_waitcnt lgkmcnt(0)" ::: "memory");
    __builtin_amdgcn_s_setprio(1);
#pragma unroll
    for (int i = 0; i < 4; ++i)
#pragma unroll
      for (int j = 0; j < 2; ++j) {
        acc[4 + i][j] = MFMA_B16(af[i * 2 + 0], bfr[j * 2 + 0], acc[4 + i][j]);
        acc[4 + i][j] = MFMA_B16(af[i * 2 + 1], bfr[j * 2 + 1], acc[4 + i][j]);
      }
    __builtin_amdgcn_s_setprio(0);
    if (kt < NT - 2) {
      asm volatile("s_waitcnt vmcnt(6)" ::: "memory");  // tile kt+1 resident
    } else {
      asm volatile("s_waitcnt vmcnt(0)" ::: "memory");  // drain tail
    }
    asm volatile("s_barrier" ::: "memory");
  }

  // ---- epilogue: normalize, bilinear gate, direct coalesced stores.
  // acc[i][j]   (j=0,1): A = y[:,2g]  for gate g = g0 + wn*32 + j*16 + fr
  // acc[i][j+2]        : B = y[:,2g+1], same lane/reg — no shuffles.
#pragma unroll
  for (int j = 0; j < 2; ++j) {
    const int gate = g0 + wn * 32 + j * 16 + fr;
    const float2 iv = *(const float2*)&invs[2 * gate];
    const float4 P  = coeff[gate];
#pragma unroll
    for (int i = 0; i < 8; ++i) {
#pragma unroll
      for (int r = 0; r < 4; ++r) {
        const float A = acc[i][j][r]     * iv.x;
        const float B = acc[i][j + 2][r] * iv.y;
        const float res = P.x + P.y * A + P.z * B + P.w * A * B;
        const int m = m0 + wm * 128 + i * 16 + cq * 4 + r;
        out[(size_t)m * NGATES + gate] = res;
      }
    }
  }
}

// ---------------------------------------------------------------------------
extern "C" void kernel_launch(void* const* d_in, const int* in_sizes, int n_in,
                              void* d_out, int out_size, void* d_ws,
                              size_t ws_size, hipStream_t stream) {
  const float* x = (const float*)d_in[0];   // [2048][2048]
  const float* w = (const float*)d_in[1];   // [16][8192]
  const float* c = (const float*)d_in[2];   // [2048][8192][2]
  float* out = (float*)d_out;               // [2048][8192]
  char* ws = (char*)d_ws;

  unsigned short* xb   = (unsigned short*)(ws);               // 8,388,608 B
  unsigned short* bT   = (unsigned short*)(ws + 8388608);     // 67,108,864 B
  float*          invs = (float*)(ws + 75497472);             // 65,536 B
  float4*         cf   = (float4*)(ws + 75563008);            // 131,072 B
  float*          ps   = (float*)(ws + 75694080);             // 262,144 B

  static bool attr_done = false;
  if (!attr_done) {
    (void)hipFuncSetAttribute(reinterpret_cast<const void*>(gemm_gate_k),
                              hipFuncAttributeMaxDynamicSharedMemorySize,
                              131072);
    (void)hipFuncSetAttribute(reinterpret_cast<const void*>(softmax_t_k),
                              hipFuncAttributeMaxDynamicSharedMemorySize,
                              69888);
    attr_done = true;
  }

  gate_coeff_k<<<NGATES / 256, 256, 0, stream>>>(w, cf);
  cvt_x_k<<<(BATCH * NIN / 4) / 256, 256, 0, stream>>>((const float4*)x,
                                                       (ushort4*)xb);
  dim3 sg(NCOL / 64, 4);
  softmax_t_k<<<sg, 256, 69888, stream>>>(c, bT, ps);
  inv_k<<<NCOL / 256, 256, 0, stream>>>(ps, invs);
  gemm_gate_k<<<512, 512, 131072, stream>>>(xb, bT, invs, cf, out);
}

// Round 3
// 347.156 us; speedup vs baseline: 1.2682x; 1.0152x over previous
//
#include <hip/hip_runtime.h>
#include <hip/hip_bf16.h>
#include <stdint.h>

#define BATCH   2048
#define NIN     2048
#define NGATES  8192
#define NCOL    16384   // NGATES*2

typedef short s16x8 __attribute__((ext_vector_type(8)));   // 8 bf16 (4 VGPRs)
typedef float f32x4 __attribute__((ext_vector_type(4)));

__device__ __forceinline__ void gload_lds16(const void* g, void* l) {
  __builtin_amdgcn_global_load_lds(
      (const __attribute__((address_space(1))) void*)g,
      (__attribute__((address_space(3))) void*)l,
      16, 0, 0);
}

__device__ __forceinline__ unsigned short f2bf(float f) {
  __hip_bfloat16 h = __float2bfloat16(f);
  return __builtin_bit_cast(unsigned short, h);
}
__device__ __forceinline__ float bf2f(unsigned int u) {
  return __bfloat162float(__builtin_bit_cast(__hip_bfloat16,
                                             (unsigned short)(u & 0xffff)));
}

// ---------------------------------------------------------------------------
// Kernel 1 (merged): blocks 0..4095: x fp32 -> bf16 row-major.
//                    blocks 4096..4127: per-gate bilinear coeffs from
//                    softmax(w[:,g]):  out = P0 + P1*A + P2*B + P3*A*B.
// Merging hides the tiny 32-block coeff grid (latency-bound on its own)
// inside the cvt grid and removes one launch.
// ---------------------------------------------------------------------------
__global__ __launch_bounds__(256) void pre_k(const float4* __restrict__ x,
                                             ushort4* __restrict__ xb,
                                             const float* __restrict__ w,
                                             float4* __restrict__ coeff) {
  const int b = blockIdx.x;
  const int t = threadIdx.x;
  if (b < 4096) {
    const int i = b * 256 + t;
    float4 v = x[i];
    ushort4 h;
    h.x = f2bf(v.x); h.y = f2bf(v.y); h.z = f2bf(v.z); h.w = f2bf(v.w);
    xb[i] = h;
  } else {
    const int g = (b - 4096) * 256 + t;
    float e[16];
    float s = 0.f;
#pragma unroll
    for (int k = 0; k < 16; ++k) { e[k] = __expf(w[k * NGATES + g]); s += e[k]; }
    const float inv = 1.0f / s;
#pragma unroll
    for (int k = 0; k < 16; ++k) e[k] *= inv;
    const float P0 = e[8] + e[9] + e[10] + e[11] + e[12] + e[13] + e[14] + e[15];
    const float P1 = e[2] + e[3] + e[6] + e[7] - e[8] - e[9] - e[12] - e[13];
    const float P2 = e[4] + e[5] + e[6] + e[7] - e[8] - e[9] - e[10] - e[11];
    const float P3 = e[1] - e[2] - e[4] - 2.f * e[6] - e[7] + e[8] + 2.f * e[9]
                   + e[11] + e[13] - e[14];
    coeff[g] = make_float4(P0, P1, P2, P3);
  }
}

// ---------------------------------------------------------------------------
// Kernel 2: e = exp(c) bf16, transposed to bT[n][k], LDS-staged (1KB
// contiguous stores). Column partial sums per row-quarter -> psums.
// Grid: (NCOL/64, 4 row-quarters of 512). Dynamic LDS 69888B.
// ---------------------------------------------------------------------------
__global__ __launch_bounds__(256) void softmax_t_k(const float* __restrict__ c,
                                                   unsigned short* __restrict__ bT,
                                                   float* __restrict__ psums) {
  extern __shared__ char sm3[];                 // 65536 tile + 4352 red
  char*  tile = sm3;                            // [64 rows][1024 B]
  float* red  = (float*)(sm3 + 65536);          // [16][68]
  const int t = threadIdx.x;
  const int ng = (t & 15) * 4;   // 4 consecutive cols
  const int kg = t >> 4;         // 0..15: 8-row chunk
  const int n0 = blockIdx.x * 64;
  const int q  = blockIdx.y;
  const float* cb = c + (size_t)n0 + ng;
  float s0 = 0.f, s1 = 0.f, s2 = 0.f, s3 = 0.f;

  float4 v[8], nv[8];
  {
    const int r0 = q * 512 + kg * 8;
#pragma unroll
    for (int d = 0; d < 8; ++d)
      v[d] = *(const float4*)&cb[(size_t)(r0 + d) * NCOL];
  }
  for (int it = 0; it < 4; ++it) {
    if (it < 3) {
      const int r1 = q * 512 + (it + 1) * 128 + kg * 8;
#pragma unroll
      for (int d = 0; d < 8; ++d)
        nv[d] = *(const float4*)&cb[(size_t)(r1 + d) * NCOL];
    }
    unsigned int u[4][4];   // [col][k-pair]
#pragma unroll
    for (int d2 = 0; d2 < 4; ++d2) {
      float4 e0 = v[2 * d2], e1 = v[2 * d2 + 1];
      unsigned int a0 = f2bf(__expf(e0.x)), b0 = f2bf(__expf(e1.x));
      unsigned int a1 = f2bf(__expf(e0.y)), b1 = f2bf(__expf(e1.y));
      unsigned int a2 = f2bf(__expf(e0.z)), b2 = f2bf(__expf(e1.z));
      unsigned int a3 = f2bf(__expf(e0.w)), b3 = f2bf(__expf(e1.w));
      s0 += bf2f(a0) + bf2f(b0);
      s1 += bf2f(a1) + bf2f(b1);
      s2 += bf2f(a2) + bf2f(b2);
      s3 += bf2f(a3) + bf2f(b3);
      u[0][d2] = a0 | (b0 << 16);
      u[1][d2] = a1 | (b1 << 16);
      u[2][d2] = a2 | (b2 << 16);
      u[3][d2] = a3 | (b3 << 16);
    }
    const int chunk = it * 16 + kg;             // 16B chunk index within row
#pragma unroll
    for (int j = 0; j < 4; ++j) {
      const int row = ng + j;
      const int sw  = (chunk & ~7) | ((chunk ^ (row >> 2)) & 7);
      uint4 pk = make_uint4(u[j][0], u[j][1], u[j][2], u[j][3]);
      *(uint4*)&tile[row * 1024 + sw * 16] = pk;
    }
    if (it < 3) {
#pragma unroll
      for (int d = 0; d < 8; ++d) v[d] = nv[d];
    }
  }
  red[kg * 68 + ng + 0] = s0;
  red[kg * 68 + ng + 1] = s1;
  red[kg * 68 + ng + 2] = s2;
  red[kg * 68 + ng + 3] = s3;
  __syncthreads();

  // Phase 2: 1KB-contiguous stores. Wave w -> rows w*16..+15; lane l -> chunk l.
  {
    const int wv = t >> 6;
    const int l  = t & 63;
#pragma unroll
    for (int r16 = 0; r16 < 16; ++r16) {
      const int row = wv * 16 + r16;
      const int sw  = (l & ~7) | ((l ^ (row >> 2)) & 7);
      uint4 vv = *(const uint4*)&tile[row * 1024 + sw * 16];
      *(uint4*)&bT[(size_t)(n0 + row) * NIN + q * 512 + l * 8] = vv;
    }
  }
  if (t < 64) {
    float tot = 0.f;
#pragma unroll
    for (int k2 = 0; k2 < 16; ++k2) tot += red[k2 * 68 + t];
    psums[(size_t)q * NCOL + n0 + t] = tot;
  }
}

// ---------------------------------------------------------------------------
// Kernel 3: 256x256-tile 8-phase bf16 MFMA GEMM (guide §5 template, m201).
// K-loop IDENTICAL to round 1/2 (132 µs, MfmaUtil 43%, 0 bank conflicts).
// Epilogue change only: reads the 4 psums row-quarters and computes the
// softmax denominators itself (inv_k kernel removed from the pipeline).
// ---------------------------------------------------------------------------
#define MFMA_B16(a, b, c) __builtin_amdgcn_mfma_f32_16x16x32_bf16(a, b, c, 0, 0, 0)

__global__ __launch_bounds__(512, 2) void gemm_gate_k(
    const unsigned short* __restrict__ xb,   // [2048][2048] bf16
    const unsigned short* __restrict__ bT,   // [16384][2048] bf16
    const float* __restrict__ ps,            // [4][16384] partial col sums
    const float4* __restrict__ coeff,        // [8192]
    float* __restrict__ out) {               // [2048][8192]
  extern __shared__ char smem[];             // 131072 B
  constexpr int NT = 32;                     // K / BK = 2048/64

  const int t  = threadIdx.x;                // 0..511
  const int l  = t & 63;
  const int w  = t >> 6;
  const int wm = w >> 2;                     // 0..1: M half
  const int wn = w & 3;                      // 0..3: N quarter
  const int fr = l & 15;
  const int cq = l >> 4;

  // XCD-bijective swizzle (512 % 8 == 0): 8 consecutive local blocks share
  // one gate-panel (L2 resident), sweep m.
  const int bid = blockIdx.x;
  const int xcd = bid & 7;
  const int loc = bid >> 3;                  // 0..63
  const int m0  = (loc & 7) * 256;
  const int g0  = (xcd * 8 + (loc >> 3)) * 128;

  // ---- stage source offsets (elements), inverse-XOR-swizzled + B-permuted
  uint32_t offA[2][2], offB[2][2];           // [unit][round]
#pragma unroll
  for (int r = 0; r < 2; ++r) {
    const int idx = r * 512 + t;             // 0..1023 -> lds (row, slot)
    const int lr  = idx >> 3;
    const int ch  = (idx & 7) ^ (lr & 7);    // chunk stored at this slot
    const int rA  = (lr & 63) + ((lr >> 6) << 7);       // A1: rows 0-63,128-191
    offA[0][r] = (uint32_t)(m0 + rA) * NIN + ch * 8;
    offA[1][r] = offA[0][r] + (uint32_t)64 * NIN;       // A2: +64
    offB[0][r] = (uint32_t)(2 * (g0 + lr)) * NIN + ch * 8;  // even col
    offB[1][r] = offB[0][r] + NIN;                          // odd col
  }

  auto issueA = [&](int u, int tt) {
    char* d = smem + ((tt & 1) << 16) + (u << 14) + t * 16;
    gload_lds16(xb + offA[u][0] + tt * 64, d);
    gload_lds16(xb + offA[u][1] + tt * 64, d + 8192);
  };
  auto issueB = [&](int u, int tt) {
    char* d = smem + ((tt & 1) << 16) + ((2 + u) << 14) + t * 16;
    gload_lds16(bT + offB[u][0] + tt * 64, d);
    gload_lds16(bT + offB[u][1] + tt * 64, d + 8192);
  };

  // ---- fragment read offsets (row*128, slot = chunk ^ (row&7))
  const int aob = (wm * 64 + fr) * 128;          // + unit*16384 + i*2048
  const int bob = 32768 + (wn * 32 + fr) * 128;  // + unit*16384 + j*2048
  const int sx0 = ((cq)     ^ (fr & 7)) * 16;    // ks=0 slot
  const int sx1 = ((cq + 4) ^ (fr & 7)) * 16;    // ks=1 slot

  f32x4 acc[8][4] = {};
  s16x8 af[8];     // current A half: 4 i x 2 ks
  s16x8 bfr[8];    // [0..3]=B1 (j=0,1 x ks), [4..7]=B2 (j=2,3 x ks)

  // ---- prologue: tile0 full + tile1 {A1,B1,B2}; A2(1) comes at kt=0 ph0
  issueA(0, 0); issueA(1, 0); issueB(0, 0); issueB(1, 0);
  issueA(0, 1); issueB(0, 1); issueB(1, 1);
  asm volatile("s_waitcnt vmcnt(6)" ::: "memory");   // tile0 landed
  asm volatile("s_barrier" ::: "memory");

  for (int kt = 0; kt < NT; ++kt) {
    char* rb = smem + ((kt & 1) << 16);

    // ===== phase 0: (i0-3, j0-1) — read A1 + B1, stage A2(kt+1)
#pragma unroll
    for (int i = 0; i < 4; ++i) {
      af[i * 2 + 0] = *(const s16x8*)(rb + aob + i * 2048 + sx0);
      af[i * 2 + 1] = *(const s16x8*)(rb + aob + i * 2048 + sx1);
    }
#pragma unroll
    for (int j = 0; j < 2; ++j) {
      bfr[j * 2 + 0] = *(const s16x8*)(rb + bob + j * 2048 + sx0);
      bfr[j * 2 + 1] = *(const s16x8*)(rb + bob + j * 2048 + sx1);
    }
    if (kt + 1 < NT) issueA(1, kt + 1);
    asm volatile("s_barrier" ::: "memory");
    asm volatile("s_waitcnt lgkmcnt(0)" ::: "memory");
    __builtin_amdgcn_s_setprio(1);
#pragma unroll
    for (int i = 0; i < 4; ++i)
#pragma unroll
      for (int j = 0; j < 2; ++j) {
        acc[i][j] = MFMA_B16(af[i * 2 + 0], bfr[j * 2 + 0], acc[i][j]);
        acc[i][j] = MFMA_B16(af[i * 2 + 1], bfr[j * 2 + 1], acc[i][j]);
      }
    __builtin_amdgcn_s_setprio(0);
    asm volatile("s_barrier" ::: "memory");

    // ===== phase 1: (i0-3, j2-3) — read B2, stage A1(kt+2)
#pragma unroll
    for (int j = 0; j < 2; ++j) {
      bfr[4 + j * 2 + 0] = *(const s16x8*)(rb + bob + 16384 + j * 2048 + sx0);
      bfr[4 + j * 2 + 1] = *(const s16x8*)(rb + bob + 16384 + j * 2048 + sx1);
    }
    if (kt + 2 < NT) issueA(0, kt + 2);
    asm volatile("s_barrier" ::: "memory");
    asm volatile("s_waitcnt lgkmcnt(0)" ::: "memory");
    __builtin_amdgcn_s_setprio(1);
#pragma unroll
    for (int i = 0; i < 4; ++i)
#pragma unroll
      for (int j = 0; j < 2; ++j) {
        acc[i][2 + j] = MFMA_B16(af[i * 2 + 0], bfr[4 + j * 2 + 0], acc[i][2 + j]);
        acc[i][2 + j] = MFMA_B16(af[i * 2 + 1], bfr[4 + j * 2 + 1], acc[i][2 + j]);
      }
    __builtin_amdgcn_s_setprio(0);
    asm volatile("s_barrier" ::: "memory");

    // ===== phase 2: (i4-7, j2-3) — read A2 into af, stage B1(kt+2)
#pragma unroll
    for (int i = 0; i < 4; ++i) {
      af[i * 2 + 0] = *(const s16x8*)(rb + 16384 + aob + i * 2048 + sx0);
      af[i * 2 + 1] = *(const s16x8*)(rb + 16384 + aob + i * 2048 + sx1);
    }
    if (kt + 2 < NT) issueB(0, kt + 2);
    asm volatile("s_barrier" ::: "memory");
    asm volatile("s_waitcnt lgkmcnt(0)" ::: "memory");
    __builtin_amdgcn_s_setprio(1);
#pragma unroll
    for (int i = 0; i < 4; ++i)
#pragma unroll
      for (int j = 0; j < 2; ++j) {
        acc[4 + i][2 + j] = MFMA_B16(af[i * 2 + 0], bfr[4 + j * 2 + 0], acc[4 + i][2 + j]);
        acc[4 + i][2 + j] = MFMA_B16(af[i * 2 + 1], bfr[4 + j * 2 + 1], acc[4 + i][2 + j]);
      }
    __builtin_amdgcn_s_setprio(0);
    asm volatile("s_barrier" ::: "memory");

    // ===== phase 3: (i4-7, j0-1) — no reads (af=A2, bfr[0..3]=B1 kept),
    //                stage B2(kt+2), counted vmcnt at tile end
    if (kt + 2 < NT) issueB(1, kt + 2);
    asm volatile("s_barrier" ::: "memory");
    asm volatile("s_waitcnt lgkmcnt(0)" ::: "memory");
    __builtin_amdgcn_s_setprio(1);
#pragma unroll
    for (int i = 0; i < 4; ++i)
#pragma unroll
      for (int j = 0; j < 2; ++j) {
        acc[4 + i][j] = MFMA_B16(af[i * 2 + 0], bfr[j * 2 + 0], acc[4 + i][j]);
        acc[4 + i][j] = MFMA_B16(af[i * 2 + 1], bfr[j * 2 + 1], acc[4 + i][j]);
      }
    __builtin_amdgcn_s_setprio(0);
    if (kt < NT - 2) {
      asm volatile("s_waitcnt vmcnt(6)" ::: "memory");  // tile kt+1 resident
    } else {
      asm volatile("s_waitcnt vmcnt(0)" ::: "memory");  // drain tail
    }
    asm volatile("s_barrier" ::: "memory");
  }

  // ---- epilogue: fold psums -> inv denominators (inv_k removed), normalize,
  // bilinear gate, direct coalesced stores. Same summation order as old
  // inv_k (p0+p1+p2+p3) for bit-identical results.
#pragma unroll
  for (int j = 0; j < 2; ++j) {
    const int gate = g0 + wn * 32 + j * 16 + fr;
    const int nA = 2 * gate, nB = 2 * gate + 1;
    const float sA = ps[nA] + ps[NCOL + nA] + ps[2 * NCOL + nA] + ps[3 * NCOL + nA];
    const float sB = ps[nB] + ps[NCOL + nB] + ps[2 * NCOL + nB] + ps[3 * NCOL + nB];
    const float ivA = 1.0f / sA;
    const float ivB = 1.0f / sB;
    const float4 P = coeff[gate];
#pragma unroll
    for (int i = 0; i < 8; ++i) {
#pragma unroll
      for (int r = 0; r < 4; ++r) {
        const float A = acc[i][j][r]     * ivA;
        const float B = acc[i][j + 2][r] * ivB;
        const float res = P.x + P.y * A + P.z * B + P.w * A * B;
        const int m = m0 + wm * 128 + i * 16 + cq * 4 + r;
        out[(size_t)m * NGATES + gate] = res;
      }
    }
  }
}

// ---------------------------------------------------------------------------
extern "C" void kernel_launch(void* const* d_in, const int* in_sizes, int n_in,
                              void* d_out, int out_size, void* d_ws,
                              size_t ws_size, hipStream_t stream) {
  const float* x = (const float*)d_in[0];   // [2048][2048]
  const float* w = (const float*)d_in[1];   // [16][8192]
  const float* c = (const float*)d_in[2];   // [2048][8192][2]
  float* out = (float*)d_out;               // [2048][8192]
  char* ws = (char*)d_ws;

  unsigned short* xb = (unsigned short*)(ws);               // 8,388,608 B
  unsigned short* bT = (unsigned short*)(ws + 8388608);     // 67,108,864 B
  float4*         cf = (float4*)(ws + 75563008);            // 131,072 B
  float*          psv = (float*)(ws + 75694080);            // 262,144 B

  static bool attr_done = false;
  if (!attr_done) {
    (void)hipFuncSetAttribute(reinterpret_cast<const void*>(gemm_gate_k),
                              hipFuncAttributeMaxDynamicSharedMemorySize,
                              131072);
    (void)hipFuncSetAttribute(reinterpret_cast<const void*>(softmax_t_k),
                              hipFuncAttributeMaxDynamicSharedMemorySize,
                              69888);
    attr_done = true;
  }

  pre_k<<<4128, 256, 0, stream>>>((const float4*)x, (ushort4*)xb, w, cf);
  dim3 sg(NCOL / 64, 4);
  softmax_t_k<<<sg, 256, 69888, stream>>>(c, bT, psv);
  gemm_gate_k<<<512, 512, 131072, stream>>>(xb, bT, psv, cf, out);
}